// Round 13
// baseline (323.120 us; speedup 1.0000x reference)
//
#include <hip/hip_runtime.h>
#include <hip/hip_bf16.h>
#include <math.h>

typedef __hip_bfloat16 bf16;

#define NNODES 20000
#define NEDGES 320000
#define DLEN   16
#define G      64
#define DW     300
#define DH     256
#define HD     128
#define G3     384
#define NCLS   2000
#define NB     4
#define TT     32
#define A2BLK  1024  // attn2 partial blocks
#define A2MID  64    // stage-1 merge outputs

#define NBLK_CVT  384
#define NBLK_GX2  1536   // 256 rows (d,b,step) x 6 j-tiles of 64
#define NBLK_HIST ((NEDGES + 255) / 256)
#define NBLK_SCAT ((NEDGES + 255) / 256)

__device__ __forceinline__ float ld(const float* p, size_t i) { return p[i]; }
__device__ __forceinline__ float ld(const bf16* p, size_t i) { return __bfloat162float(p[i]); }
__device__ __forceinline__ void st(float* p, size_t i, float v) { p[i] = v; }
__device__ __forceinline__ void st(bf16* p, size_t i, float v) { p[i] = __float2bfloat16(v); }
__device__ __forceinline__ float relu(float x) { return (x < 0.f) ? 0.f : x; }

struct __align__(8) bf4 { bf16 x, y, z, w; };

// ---------------- workspace layout (float words) ----------------
#define OFF_FLAG  ((size_t)0)                         // 4
#define OFF_GX    (OFF_FLAG + 4)                      // 98304
#define OFF_WHF   (OFF_GX   + 2*NB*TT*G3)             // 98304
#define OFF_QEMB  (OFF_WHF  + 2*HD*G3)                // 1024
#define OFF_QG    (OFF_QEMB + NB*DH)                  // 256
#define OFF_NF    (OFF_QG   + NB*G)                   // bf16 both pre- and post-RGCN
#define OFF_HB    (OFF_NF   + (size_t)NB*NNODES*G)    // bf16 [n][b][g]
#define OFF_PART  (OFF_HB   + (size_t)NB*NNODES*G)    // 1024*4*66
#define OFF_PART2 (OFF_PART + (size_t)A2BLK*NB*66)    // 64*4*66
#define OFF_DEG   (OFF_PART2+ (size_t)A2MID*NB*66)    // int 20000
#define OFF_OFFS  (OFF_DEG  + NNODES)                 // int 20008
#define OFF_CUR   (OFF_OFFS + NNODES + 8)             // int 20000
#define OFF_SSRC  (OFF_CUR  + NNODES)                 // int 320000
#define OFF_SCO   (OFF_SSRC + NEDGES)                 // float 320000
#define OFF_HID   (OFF_SCO  + NEDGES)                 // 4096

// ---------------- init: dtype sniff + zero deg ----------------
__global__ void k_init(const unsigned* probe, int* flag, int* deg) {
    int i = blockIdx.x * 256 + threadIdx.x;
    if (i < NNODES) deg[i] = 0;
    if (blockIdx.x == 0 && threadIdx.x < 64) {
        int cnt = 0;
        for (int k = threadIdx.x; k < 4096; k += 64) {
            unsigned lo = probe[k] & 0xFFFFu;
            unsigned e = (lo >> 7) & 0xFFu;
            cnt += (e >= 0x66u && e <= 0x7Eu) ? 1 : 0;
        }
#pragma unroll
        for (int off = 1; off < 64; off <<= 1) cnt += __shfl_xor(cnt, off, 64);
        if (threadIdx.x == 0) *flag = (2 * cnt > 4096) ? 1 : 0;   // 1 = bf16
    }
}

// ---------------- fused prep: cvt | gx (K-split) | hist --------------------
template <typename T>
__device__ void cvt_body(int id, const void* Whf_, const void* Whb_, float* whf) {
    if (id >= 2 * HD * G3) return;
    int d = id / (HD * G3), r = id % (HD * G3);
    const T* W = (const T*)(d ? Whb_ : Whf_);
    whf[id] = ld(W, (size_t)r);
}

template <typename T>
__device__ void gx2_body(int bx2, const int* questions, const void* emb_word_,
                         const void* Wxf_, const void* bxf_,
                         const void* Wxb_, const void* bxb_, float* gx,
                         float* xs, float* psum) {
    int tid = threadIdx.x;
    int jt = bx2 % 6;
    int rid = bx2 / 6;                  // 0..255
    int step = rid & 31;
    int b = (rid >> 5) & 3;
    int d = rid >> 7;
    int t = d ? (TT - 1 - step) : step;
    int tok = questions[b * TT + t];
    const T* row = (const T*)emb_word_ + (size_t)tok * DW;
    for (int k = tid; k < DW; k += 256) xs[k] = ld(row, (size_t)k);
    __syncthreads();
    int lane = tid & 63, phase = tid >> 6;
    int j = jt * 64 + lane;
    const T* Wx = (const T*)(d ? Wxb_ : Wxf_);
    float acc = 0.f;
    int k0 = phase * 75;
#pragma unroll 15
    for (int kk = 0; kk < 75; kk++) {
        int k = k0 + kk;
        acc += xs[k] * ld(Wx, (size_t)k * G3 + j);
    }
    psum[tid] = acc;
    __syncthreads();
    if (phase == 0) {
        const T* bx = (const T*)(d ? bxb_ : bxf_);
        float tot = ld(bx, (size_t)j)
                  + psum[lane] + psum[64 + lane] + psum[128 + lane] + psum[192 + lane];
        gx[(size_t)rid * G3 + j] = tot;
    }
}

__global__ void k_prep(const int* flag, const void* Whf, const void* Whb, float* whf,
                       const int* questions, const void* emb_word,
                       const void* Wxf, const void* bxf,
                       const void* Wxb, const void* bxb, float* gx,
                       const int* edge_dst, int* deg) {
    __shared__ float xs[DW];
    __shared__ float psum[256];
    int bx = blockIdx.x;
    int tid = threadIdx.x;
    if (bx < NBLK_CVT) {
        int id = bx * 256 + tid;
        if (*flag) cvt_body<bf16>(id, Whf, Whb, whf);
        else       cvt_body<float>(id, Whf, Whb, whf);
    } else if (bx < NBLK_CVT + NBLK_GX2) {
        int bx2 = bx - NBLK_CVT;
        if (*flag) gx2_body<bf16>(bx2, questions, emb_word, Wxf, bxf, Wxb, bxb, gx, xs, psum);
        else       gx2_body<float>(bx2, questions, emb_word, Wxf, bxf, Wxb, bxb, gx, xs, psum);
    } else {
        int e = (bx - NBLK_CVT - NBLK_GX2) * 256 + tid;
        if (e < NEDGES) atomicAdd(&deg[edge_dst[e]], 1);
    }
}

// ---------------- GRU scan (blocks 0..7) + CSR scan (block 8) --------------
template <typename T>
__device__ void gru_body(const int* questions, const float* gx, const float* whf,
                         const void* bhf_, const void* bhb_, float* qemb,
                         float* hsm, float* ghs) {
    int tid = threadIdx.x;
    int d = blockIdx.x >> 2, b = blockIdx.x & 3;
    int half = tid / G3, j = tid - half * G3;
    const float* wh = whf + (size_t)d * HD * G3 + (size_t)half * 64 * G3 + j;
    float w[64];
#pragma unroll
    for (int m = 0; m < 64; m++) w[m] = wh[(size_t)m * G3];
    const T* bh = (const T*)(d ? bhb_ : bhf_);
    float bhj = (half == 0) ? ld(bh, (size_t)j) : 0.f;
    if (tid < HD) hsm[tid] = 0.f;
    const float* gxb = gx + ((size_t)(d * NB + b)) * TT * G3;
    __syncthreads();
    const float4* h4 = (const float4*)(hsm + half * 64);
    for (int step = 0; step < TT; step++) {
        float acc = bhj;
#pragma unroll
        for (int m4 = 0; m4 < 16; m4++) {
            float4 hp = h4[m4];
            acc = fmaf(hp.x, w[4 * m4 + 0], acc);
            acc = fmaf(hp.y, w[4 * m4 + 1], acc);
            acc = fmaf(hp.z, w[4 * m4 + 2], acc);
            acc = fmaf(hp.w, w[4 * m4 + 3], acc);
        }
        ghs[half * G3 + j] = acc;
        __syncthreads();
        if (tid < HD) {
            const float* gxp = gxb + step * G3;
            int t = d ? (TT - 1 - step) : step;
            bool msk = questions[b * TT + t] != 0;
            float gr = ghs[tid] + ghs[G3 + tid];
            float gz = ghs[HD + tid] + ghs[G3 + HD + tid];
            float gn = ghs[2 * HD + tid] + ghs[G3 + 2 * HD + tid];
            float r = 1.f / (1.f + expf(-(gxp[tid] + gr)));
            float z = 1.f / (1.f + expf(-(gxp[HD + tid] + gz)));
            float n = tanhf(gxp[2 * HD + tid] + r * gn);
            float hn = (1.f - z) * n + z * hsm[tid];
            if (msk) hsm[tid] = hn;
        }
        __syncthreads();
    }
    if (tid < HD) qemb[b * DH + d * HD + tid] = hsm[tid];
}

// exclusive int scan of deg with 768 threads x 27 elems (exact)
__device__ void scan_body(const int* deg, int* offs, int* cur, int* wtot) {
    int t = threadIdx.x;                 // 0..767
    int lane = t & 63, wave = t >> 6;    // 12 waves
    int c[27];
    int base = t * 27;
    int run = 0;
#pragma unroll
    for (int i = 0; i < 27; i++) {
        int v = (base + i < NNODES) ? deg[base + i] : 0;
        c[i] = run;
        run += v;
    }
    int myrun = run, inc = run;
#pragma unroll
    for (int off = 1; off < 64; off <<= 1) {
        int u = __shfl_up(inc, off, 64);
        if (lane >= off) inc += u;
    }
    if (lane == 63) wtot[wave] = inc;
    __syncthreads();
    if (t == 0) {
        int s = 0;
#pragma unroll
        for (int i = 0; i < 12; i++) { int v = wtot[i]; wtot[i] = s; s += v; }
        offs[NNODES] = s;
    }
    __syncthreads();
    int ebase = wtot[wave] + inc - myrun;
#pragma unroll
    for (int i = 0; i < 27; i++) {
        if (base + i < NNODES) {
            offs[base + i] = ebase + c[i];
            cur[base + i] = ebase + c[i];
        }
    }
}

__global__ __launch_bounds__(2 * G3) void k_gru(const int* flag, const int* questions,
                                                const float* gx, const float* whf,
                                                const void* bhf, const void* bhb, float* qemb,
                                                const int* deg, int* offs, int* cur) {
    __shared__ __align__(16) float hsm[HD];
    __shared__ float ghs[2 * G3];
    __shared__ int wtot[12];
    if (blockIdx.x < 8) {
        if (*flag) gru_body<bf16>(questions, gx, whf, bhf, bhb, qemb, hsm, ghs);
        else       gru_body<float>(questions, gx, whf, bhf, bhb, qemb, hsm, ghs);
    } else {
        scan_body(deg, offs, cur, wtot);
    }
}

// ---------------- q_g = q_emb @ W_hg + b_hg (1 block) ----------------
template <typename T>
__device__ void qg_body(const float* qemb, const void* W_hg_, const void* b_hg_, float* qg) {
    int tid = threadIdx.x;
    int b = tid >> 6, g = tid & 63;
    const T* W = (const T*)W_hg_;
    float acc = ld((const T*)b_hg_, (size_t)g);
#pragma unroll 4
    for (int i = 0; i < DH; i++) acc += qemb[b * DH + i] * ld(W, (size_t)i * G + g);
    qg[b * G + g] = acc;
}
__global__ void k_qg(const int* flag, const float* qemb, const void* W_hg,
                     const void* b_hg, float* qg) {
    if (*flag) qg_body<bf16>(qemb, W_hg, b_hg, qg);
    else       qg_body<float>(qemb, W_hg, b_hg, qg);
}

// ---------------- fused: scatter (blocks 0..1249) | attn1 (rest) -----------
template <typename T>
__device__ void scatter_body(int e, const int* src, const int* dst, const int* typ,
                             const void* w_comp_, int* cur, int* ssrc, float* sco) {
    if (e < NEDGES) {
        int dd = dst[e];
        int pos = atomicAdd(&cur[dd], 1);
        ssrc[pos] = src[e];
        sco[pos] = ld((const T*)w_comp_, (size_t)typ[e]);
    }
}

template <typename T>
__device__ void attn1_body(int nb4, const int* node_descs, const void* emb_desc_,
                           const float* qg, bf16* nf16,
                           float* dsm, float* attn_s, float* qgs) {
    int tid = threadIdx.x;
    if (tid < NB * G) qgs[tid] = qg[tid];
    __syncthreads();
    const T* emb_desc = (const T*)emb_desc_;
    int w = tid >> 6, lane = tid & 63;
    int n = nb4 * 4 + w;
    float dreg[DLEN];
    const int* nd = node_descs + n * DLEN;
    float* dw = dsm + (size_t)w * DLEN * 68;
#pragma unroll
    for (int l = 0; l < DLEN; l++) {
        int idx = nd[l];
        float v = ld(emb_desc, (size_t)idx * G + lane);
        dreg[l] = v;
        dw[l * 68 + lane] = v;
    }
    int lb = lane >> 4, ll = lane & 15;
    float acc = 0.f;
#pragma unroll
    for (int i = 0; i < 16; i++) {
        float4 a = *(const float4*)&dw[ll * 68 + 4 * i];
        float4 q = *(const float4*)&qgs[lb * G + 4 * i];
        acc = fmaf(a.x, q.x, acc);
        acc = fmaf(a.y, q.y, acc);
        acc = fmaf(a.z, q.z, acc);
        acc = fmaf(a.w, q.w, acc);
    }
    float mx = acc;
#pragma unroll
    for (int off = 1; off < 16; off <<= 1) mx = fmaxf(mx, __shfl_xor(mx, off, 64));
    float e = expf(acc - mx);
    float s = e;
#pragma unroll
    for (int off = 1; off < 16; off <<= 1) s += __shfl_xor(s, off, 64);
    attn_s[w * 64 + lane] = e / s;
#pragma unroll
    for (int b = 0; b < NB; b++) {
        float a = 0.f;
#pragma unroll
        for (int l = 0; l < DLEN; l++) a += attn_s[w * 64 + b * 16 + l] * dreg[l];
        nf16[((size_t)b * NNODES + n) * G + lane] = __float2bfloat16(a);
    }
}

__global__ __launch_bounds__(256) void k_sc_attn1(const int* flag,
                                                  const int* src, const int* dst, const int* typ,
                                                  const void* w_comp, int* cur,
                                                  int* ssrc, float* sco,
                                                  const int* node_descs, const void* emb_desc,
                                                  const float* qg, bf16* nf16) {
    __shared__ __align__(16) float dsm[4 * DLEN * 68];
    __shared__ float attn_s[4 * 64];
    __shared__ __align__(16) float qgs[NB * G];
    int bx = blockIdx.x;
    if (bx < NBLK_SCAT) {
        int e = bx * 256 + threadIdx.x;
        if (*flag) scatter_body<bf16>(e, src, dst, typ, w_comp, cur, ssrc, sco);
        else       scatter_body<float>(e, src, dst, typ, w_comp, cur, ssrc, sco);
    } else {
        int nb4 = bx - NBLK_SCAT;
        if (*flag) attn1_body<bf16>(nb4, node_descs, emb_desc, qg, nf16, dsm, attn_s, qgs);
        else       attn1_body<float>(nb4, node_descs, emb_desc, qg, nf16, dsm, attn_s, qgs);
    }
}

// ---------------- hb = nf16 @ bases[0] : tiled register GEMM, bf16 out -----
template <typename T>
__device__ void hbg_body(const bf16* nf16, const void* bases_, bf16* hb16,
                         float* as, float* bs) {
    int tid = threadIdx.x;
    const T* bases = (const T*)bases_;
    for (int i = tid; i < G * G; i += 256) bs[(i >> 6) * 68 + (i & 63)] = ld(bases, (size_t)i);
    size_t r0 = (size_t)blockIdx.x * 64;
    const bf4* gA = (const bf4*)(nf16 + r0 * G);
#pragma unroll
    for (int i = 0; i < 4; i++) {
        int c = tid + i * 256;
        int row = c >> 4, col4 = c & 15;
        bf4 v = gA[c];
        float4 f;
        f.x = __bfloat162float(v.x);
        f.y = __bfloat162float(v.y);
        f.z = __bfloat162float(v.z);
        f.w = __bfloat162float(v.w);
        *(float4*)&as[row * 68 + col4 * 4] = f;
    }
    __syncthreads();
    int tx = tid & 15, ty = tid >> 4;
    float acc[4][4];
#pragma unroll
    for (int i = 0; i < 4; i++)
#pragma unroll
        for (int j = 0; j < 4; j++) acc[i][j] = 0.f;
#pragma unroll 4
    for (int g4 = 0; g4 < 16; g4++) {
        float4 b0 = *(const float4*)&bs[(4 * g4 + 0) * 68 + tx * 4];
        float4 b1 = *(const float4*)&bs[(4 * g4 + 1) * 68 + tx * 4];
        float4 b2 = *(const float4*)&bs[(4 * g4 + 2) * 68 + tx * 4];
        float4 b3 = *(const float4*)&bs[(4 * g4 + 3) * 68 + tx * 4];
#pragma unroll
        for (int i = 0; i < 4; i++) {
            float4 a = *(const float4*)&as[(ty * 4 + i) * 68 + g4 * 4];
            acc[i][0] = fmaf(a.x, b0.x, acc[i][0]);
            acc[i][0] = fmaf(a.y, b1.x, acc[i][0]);
            acc[i][0] = fmaf(a.z, b2.x, acc[i][0]);
            acc[i][0] = fmaf(a.w, b3.x, acc[i][0]);
            acc[i][1] = fmaf(a.x, b0.y, acc[i][1]);
            acc[i][1] = fmaf(a.y, b1.y, acc[i][1]);
            acc[i][1] = fmaf(a.z, b2.y, acc[i][1]);
            acc[i][1] = fmaf(a.w, b3.y, acc[i][1]);
            acc[i][2] = fmaf(a.x, b0.z, acc[i][2]);
            acc[i][2] = fmaf(a.y, b1.z, acc[i][2]);
            acc[i][2] = fmaf(a.z, b2.z, acc[i][2]);
            acc[i][2] = fmaf(a.w, b3.z, acc[i][2]);
            acc[i][3] = fmaf(a.x, b0.w, acc[i][3]);
            acc[i][3] = fmaf(a.y, b1.w, acc[i][3]);
            acc[i][3] = fmaf(a.z, b2.w, acc[i][3]);
            acc[i][3] = fmaf(a.w, b3.w, acc[i][3]);
        }
    }
#pragma unroll
    for (int i = 0; i < 4; i++) {
        size_t r = r0 + ty * 4 + i;
        int b = (int)(r / NNODES);
        int n = (int)(r - (size_t)b * NNODES);
        bf4 o;
        o.x = __float2bfloat16(acc[i][0]);
        o.y = __float2bfloat16(acc[i][1]);
        o.z = __float2bfloat16(acc[i][2]);
        o.w = __float2bfloat16(acc[i][3]);
        *(bf4*)&hb16[((size_t)n * NB + b) * G + tx * 4] = o;
    }
}
__global__ __launch_bounds__(256) void k_hbg(const int* flag, const bf16* nf16,
                                             const void* bases, bf16* hb16) {
    __shared__ __align__(16) float as[64 * 68];
    __shared__ __align__(16) float bs[64 * 68];
    if (*flag) hbg_body<bf16>(nf16, bases, hb16, as, bs);
    else       hbg_body<float>(nf16, bases, hb16, as, bs);
}

// ---------------- RGCN aggregate: 16/8/4/1 unroll cascade, bf16 out --------
template <typename T>
__device__ void agg_body(const bf16* hb16, const int* offs, const int* ssrc,
                         const float* sco, const void* bias_, bf16* out_nf16) {
    int tid = threadIdx.x;
    int b = tid >> 6, g = tid & 63;
    int dn = blockIdx.x;
    int s0 = offs[dn], s1 = offs[dn + 1];
    int boff = b * G + g;
    float acc = 0.f;
    int p = s0;
    for (; p + 15 < s1; p += 16) {
        int ix[16]; float co[16]; float x[16];
#pragma unroll
        for (int k = 0; k < 16; k++) { ix[k] = ssrc[p + k]; co[k] = sco[p + k]; }
#pragma unroll
        for (int k = 0; k < 16; k++) x[k] = __bfloat162float(hb16[(size_t)ix[k] * (NB * G) + boff]);
#pragma unroll
        for (int k = 0; k < 16; k++) acc += co[k] * x[k];
    }
    for (; p + 7 < s1; p += 8) {
        int ix[8]; float co[8]; float x[8];
#pragma unroll
        for (int k = 0; k < 8; k++) { ix[k] = ssrc[p + k]; co[k] = sco[p + k]; }
#pragma unroll
        for (int k = 0; k < 8; k++) x[k] = __bfloat162float(hb16[(size_t)ix[k] * (NB * G) + boff]);
#pragma unroll
        for (int k = 0; k < 8; k++) acc += co[k] * x[k];
    }
    for (; p + 3 < s1; p += 4) {
        int ix[4]; float co[4]; float x[4];
#pragma unroll
        for (int k = 0; k < 4; k++) { ix[k] = ssrc[p + k]; co[k] = sco[p + k]; }
#pragma unroll
        for (int k = 0; k < 4; k++) x[k] = __bfloat162float(hb16[(size_t)ix[k] * (NB * G) + boff]);
#pragma unroll
        for (int k = 0; k < 4; k++) acc += co[k] * x[k];
    }
    for (; p < s1; p++)
        acc += sco[p] * __bfloat162float(hb16[(size_t)ssrc[p] * (NB * G) + boff]);
    out_nf16[((size_t)b * NNODES + dn) * G + g] =
        __float2bfloat16(relu(acc + ld((const T*)bias_, (size_t)g)));
}
__global__ __launch_bounds__(256) void k_agg(const int* flag, const bf16* hb16, const int* offs,
                                             const int* ssrc, const float* sco,
                                             const void* bias, bf16* out_nf16) {
    if (*flag) agg_body<bf16>(hb16, offs, ssrc, sco, bias, out_nf16);
    else       agg_body<float>(hb16, offs, ssrc, sco, bias, out_nf16);
}

// ---------------- attn2: single-pass online softmax over bf16 rg -----------
__device__ __forceinline__ void a2_update(float& M, float& L, float& A, float p, float v) {
    if (p > M) {
        float s = expf(M - p);
        A *= s; L *= s; M = p;
    }
    float e = expf(p - M);
    L += e;
    A = fmaf(e, v, A);
}

__global__ __launch_bounds__(256) void k_attn2(const bf16* rg, const float* qg, float* part) {
    int tid = threadIdx.x;
    int b = tid >> 6, lane = tid & 63;
    float q = qg[b * G + lane];
    int chunk = (NNODES + A2BLK - 1) / A2BLK;
    int n0 = blockIdx.x * chunk;
    int n1 = min(n0 + chunk, NNODES);
    const bf16* base = rg + (size_t)b * NNODES * G + lane;
    float M = -3.4e38f, L = 0.f, A = 0.f;
    int n = n0;
    for (; n + 3 < n1; n += 4) {
        float v0 = __bfloat162float(base[(size_t)(n + 0) * G]);
        float v1 = __bfloat162float(base[(size_t)(n + 1) * G]);
        float v2 = __bfloat162float(base[(size_t)(n + 2) * G]);
        float v3 = __bfloat162float(base[(size_t)(n + 3) * G]);
        float p0 = v0 * q, p1 = v1 * q, p2 = v2 * q, p3 = v3 * q;
#pragma unroll
        for (int off = 32; off >= 1; off >>= 1) {
            p0 += __shfl_xor(p0, off, 64);
            p1 += __shfl_xor(p1, off, 64);
            p2 += __shfl_xor(p2, off, 64);
            p3 += __shfl_xor(p3, off, 64);
        }
        a2_update(M, L, A, p0, v0);
        a2_update(M, L, A, p1, v1);
        a2_update(M, L, A, p2, v2);
        a2_update(M, L, A, p3, v3);
    }
    for (; n < n1; n++) {
        float v = __bfloat162float(base[(size_t)n * G]);
        float p = v * q;
#pragma unroll
        for (int off = 32; off >= 1; off >>= 1) p += __shfl_xor(p, off, 64);
        a2_update(M, L, A, p, v);
    }
    float* pp = part + ((size_t)blockIdx.x * NB + b) * 66;
    if (lane == 0) { pp[0] = M; pp[1] = L; }
    pp[2 + lane] = A;
}

// stage-1 merge: A2BLK -> A2MID partials
__global__ void k_attn2m(const float* part, float* part2) {
    int tid = threadIdx.x;
    int b = tid >> 6, lane = tid & 63;
    int grp = blockIdx.x;
    float M = -3.4e38f, L = 0.f, A = 0.f;
    for (int i = 0; i < A2BLK / A2MID; i++) {
        const float* pp = part + ((size_t)(grp * (A2BLK / A2MID) + i) * NB + b) * 66;
        float m = pp[0], l = pp[1], a = pp[2 + lane];
        float mn = fmaxf(M, m);
        float e1 = expf(M - mn), e2 = expf(m - mn);
        A = A * e1 + a * e2;
        L = L * e1 + l * e2;
        M = mn;
    }
    float* pq = part2 + ((size_t)grp * NB + b) * 66;
    if (lane == 0) { pq[0] = M; pq[1] = L; }
    pq[2 + lane] = A;
}

// ---------------- fc1 with inline final attn2 merge ----------------
template <typename T>
__device__ void fc1_body(const float* part2, const float* qemb,
                         const void* W1_, const void* b1_, float* hid,
                         float* feat, float* psum) {
    int tid = threadIdx.x;
    int b = blockIdx.x >> 4, tile = blockIdx.x & 15;
    if (tid < 64) {
        float M = -3.4e38f, L = 0.f, A = 0.f;
        for (int p = 0; p < A2MID; p++) {
            const float* pp = part2 + ((size_t)p * NB + b) * 66;
            float m = pp[0], l = pp[1], a = pp[2 + tid];
            float mn = fmaxf(M, m);
            float e1 = expf(M - mn), e2 = expf(m - mn);
            A = A * e1 + a * e2;
            L = L * e1 + l * e2;
            M = mn;
        }
        feat[tid] = A / L;
        feat[tid + 256] = qemb[b * DH + tid + 192];
    } else {
        feat[tid] = qemb[b * DH + tid - G];
    }
    __syncthreads();
    int lane = tid & 63, phase = tid >> 6;
    int u = tile * 64 + lane;
    const T* W1 = (const T*)W1_;
    float acc = 0.f;
#pragma unroll 8
    for (int kk = 0; kk < 80; kk++) {
        int k = phase * 80 + kk;
        acc += feat[k] * ld(W1, (size_t)k * 1024 + u);
    }
    psum[tid] = acc;
    __syncthreads();
    if (phase == 0) {
        float tot = psum[lane] + psum[64 + lane] + psum[128 + lane] + psum[192 + lane]
                  + ld((const T*)b1_, (size_t)u);
        hid[b * 1024 + u] = relu(tot);
    }
}
__global__ __launch_bounds__(256) void k_fc1(const int* flag, const float* part2,
                                             const float* qemb, const void* W1, const void* b1,
                                             float* hid) {
    __shared__ float feat[320];
    __shared__ float psum[256];
    if (*flag) fc1_body<bf16>(part2, qemb, W1, b1, hid, feat, psum);
    else       fc1_body<float>(part2, qemb, W1, b1, hid, feat, psum);
}

// ---------------- classifier: fc2, batched c-tile (W2 read shared by 4 b) --
// grid = 32 blocks (c-tiles of 64); block 256 = 64 c-lanes x 4 u-phases.
// Per-(b,c) accumulation order identical to previous version (u ascending in
// phase, phases summed in fixed order, bias last) -> bit-identical math.
template <typename T>
__device__ void fc2_body(const float* hid, const void* W2_, const void* b2_, void* out_,
                         float* hs, float* psum) {
    int tid = threadIdx.x;
    int tile = blockIdx.x;
#pragma unroll
    for (int i = 0; i < 16; i++) hs[tid + 256 * i] = hid[tid + 256 * i];
    __syncthreads();
    int lane = tid & 63, phase = tid >> 6;
    int c = tile * 64 + lane;
    bool ok = (c < NCLS);
    const T* W2 = (const T*)W2_;
    float a0 = 0.f, a1 = 0.f, a2 = 0.f, a3 = 0.f;
    if (ok) {
#pragma unroll 8
        for (int uu = 0; uu < 256; uu++) {
            int u = phase * 256 + uu;
            float w = ld(W2, (size_t)u * NCLS + c);
            a0 += hs[u] * w;
            a1 += hs[1024 + u] * w;
            a2 += hs[2048 + u] * w;
            a3 += hs[3072 + u] * w;
        }
    }
    psum[tid] = a0;
    psum[256 + tid] = a1;
    psum[512 + tid] = a2;
    psum[768 + tid] = a3;
    __syncthreads();
    if (phase == 0 && ok) {
        float bb = ld((const T*)b2_, (size_t)c);
#pragma unroll
        for (int b = 0; b < NB; b++) {
            float* ps = psum + b * 256;
            float tot = ps[lane] + ps[64 + lane] + ps[128 + lane] + ps[192 + lane] + bb;
            st((T*)out_, (size_t)b * NCLS + c, tot);
        }
    }
}
__global__ __launch_bounds__(256) void k_fc2(const int* flag, const float* hid,
                                             const void* W2, const void* b2v, void* out) {
    __shared__ float hs[4096];
    __shared__ float psum[1024];
    if (*flag) fc2_body<bf16>(hid, W2, b2v, out, hs, psum);
    else       fc2_body<float>(hid, W2, b2v, out, hs, psum);
}

extern "C" void kernel_launch(void* const* d_in, const int* in_sizes, int n_in,
                              void* d_out, int out_size, void* d_ws, size_t ws_size,
                              hipStream_t stream) {
    const int* questions  = (const int*)d_in[0];
    const int* node_descs = (const int*)d_in[1];
    const int* edge_src   = (const int*)d_in[2];
    const int* edge_dst   = (const int*)d_in[3];
    const int* edge_type  = (const int*)d_in[4];
    const void* emb_word  = d_in[5];
    const void* emb_desc  = d_in[6];
    const void* Wx_f = d_in[7];
    const void* Wh_f = d_in[8];
    const void* bx_f = d_in[9];
    const void* bh_f = d_in[10];
    const void* Wx_b = d_in[11];
    const void* Wh_b = d_in[12];
    const void* bx_b = d_in[13];
    const void* bh_b = d_in[14];
    const void* W_hg = d_in[15];
    const void* b_hg = d_in[16];
    const void* bases = d_in[17];
    const void* w_comp = d_in[18];
    const void* rgcn_bias = d_in[19];
    const void* W1 = d_in[20];
    const void* b1 = d_in[21];
    const void* W2 = d_in[22];
    const void* b2 = d_in[23];

    float* ws = (float*)d_ws;
    int*      flag  = (int*)(ws + OFF_FLAG);
    float*    gx    = ws + OFF_GX;
    float*    whf   = ws + OFF_WHF;
    float*    qemb  = ws + OFF_QEMB;
    float*    qg    = ws + OFF_QG;
    bf16*     nf16  = (bf16*)(ws + OFF_NF);
    bf16*     hb16  = (bf16*)(ws + OFF_HB);
    float*    part  = ws + OFF_PART;
    float*    part2 = ws + OFF_PART2;
    int*      deg   = (int*)(ws + OFF_DEG);
    int*      offs  = (int*)(ws + OFF_OFFS);
    int*      cur   = (int*)(ws + OFF_CUR);
    int*      ssrc  = (int*)(ws + OFF_SSRC);
    float*    sco   = ws + OFF_SCO;
    float*    hid   = ws + OFF_HID;

    hipLaunchKernelGGL(k_init, dim3(80), dim3(256), 0, stream,
                       (const unsigned*)emb_word, flag, deg);
    hipLaunchKernelGGL(k_prep, dim3(NBLK_CVT + NBLK_GX2 + NBLK_HIST), dim3(256), 0, stream,
                       flag, Wh_f, Wh_b, whf,
                       questions, emb_word, Wx_f, bx_f, Wx_b, bx_b, gx,
                       edge_dst, deg);
    hipLaunchKernelGGL(k_gru, dim3(9), dim3(2 * G3), 0, stream,
                       flag, questions, gx, whf, bh_f, bh_b, qemb, deg, offs, cur);
    hipLaunchKernelGGL(k_qg, dim3(1), dim3(256), 0, stream, flag, qemb, W_hg, b_hg, qg);
    hipLaunchKernelGGL(k_sc_attn1, dim3(NBLK_SCAT + NNODES / 4), dim3(256), 0, stream,
                       flag, edge_src, edge_dst, edge_type, w_comp, cur, ssrc, sco,
                       node_descs, emb_desc, qg, nf16);
    hipLaunchKernelGGL(k_hbg, dim3(NB * NNODES / 64), dim3(256), 0, stream,
                       flag, nf16, bases, hb16);
    hipLaunchKernelGGL(k_agg, dim3(NNODES), dim3(256), 0, stream,
                       flag, hb16, offs, ssrc, sco, rgcn_bias, nf16);
    hipLaunchKernelGGL(k_attn2, dim3(A2BLK), dim3(256), 0, stream, nf16, qg, part);
    hipLaunchKernelGGL(k_attn2m, dim3(A2MID), dim3(256), 0, stream, part, part2);
    hipLaunchKernelGGL(k_fc1, dim3(NB * 16), dim3(256), 0, stream,
                       flag, part2, qemb, W1, b1, hid);
    hipLaunchKernelGGL(k_fc2, dim3(32), dim3(256), 0, stream,
                       flag, hid, W2, b2, d_out);
}

// Round 14
// 312.359 us; speedup vs baseline: 1.0344x; 1.0344x over previous
//
#include <hip/hip_runtime.h>
#include <hip/hip_bf16.h>
#include <math.h>

typedef __hip_bfloat16 bf16;

#define NNODES 20000
#define NEDGES 320000
#define DLEN   16
#define G      64
#define DW     300
#define DH     256
#define HD     128
#define G3     384
#define NCLS   2000
#define NB     4
#define TT     32
#define A2BLK  1024  // attn2 partial blocks
#define A2MID  64    // stage-1 merge outputs

#define NBLK_CVT  384
#define NBLK_GX2  1536   // 256 rows (d,b,step) x 6 j-tiles of 64
#define NBLK_HIST ((NEDGES + 255) / 256)
#define NBLK_SCAT ((NEDGES + 255) / 256)

__device__ __forceinline__ float ld(const float* p, size_t i) { return p[i]; }
__device__ __forceinline__ float ld(const bf16* p, size_t i) { return __bfloat162float(p[i]); }
__device__ __forceinline__ void st(float* p, size_t i, float v) { p[i] = v; }
__device__ __forceinline__ void st(bf16* p, size_t i, float v) { p[i] = __float2bfloat16(v); }
__device__ __forceinline__ float relu(float x) { return (x < 0.f) ? 0.f : x; }

struct __align__(8) bf4 { bf16 x, y, z, w; };

// ---------------- workspace layout (float words) ----------------
#define OFF_FLAG  ((size_t)0)                         // 4
#define OFF_GX    (OFF_FLAG + 4)                      // 98304
#define OFF_WHF   (OFF_GX   + 2*NB*TT*G3)             // 98304
#define OFF_QEMB  (OFF_WHF  + 2*HD*G3)                // 1024
#define OFF_QG    (OFF_QEMB + NB*DH)                  // 256
#define OFF_NF    (OFF_QG   + NB*G)                   // bf16 pre+post RGCN
#define OFF_HB    (OFF_NF   + (size_t)NB*NNODES*G)    // bf16 [n][b][g]
#define OFF_PART  (OFF_HB   + (size_t)NB*NNODES*G)    // 1024*4*66
#define OFF_PART2 (OFF_PART + (size_t)A2BLK*NB*66)    // 64*4*66
#define OFF_DEG   (OFF_PART2+ (size_t)A2MID*NB*66)    // int 20000
#define OFF_OFFS  (OFF_DEG  + NNODES)                 // int 20008
#define OFF_RANK  (OFF_OFFS + NNODES + 8)             // int 320000
#define OFF_EPACK (OFF_RANK + NEDGES)                 // int2 x 320000 (8B aligned)
#define OFF_HID   (OFF_EPACK + 2*(size_t)NEDGES)      // 4096

// ---------------- init: dtype sniff + zero deg ----------------
__global__ void k_init(const unsigned* probe, int* flag, int* deg) {
    int i = blockIdx.x * 256 + threadIdx.x;
    if (i < NNODES) deg[i] = 0;
    if (blockIdx.x == 0 && threadIdx.x < 64) {
        int cnt = 0;
        for (int k = threadIdx.x; k < 4096; k += 64) {
            unsigned lo = probe[k] & 0xFFFFu;
            unsigned e = (lo >> 7) & 0xFFu;
            cnt += (e >= 0x66u && e <= 0x7Eu) ? 1 : 0;
        }
#pragma unroll
        for (int off = 1; off < 64; off <<= 1) cnt += __shfl_xor(cnt, off, 64);
        if (threadIdx.x == 0) *flag = (2 * cnt > 4096) ? 1 : 0;   // 1 = bf16
    }
}

// ---------------- fused prep: cvt | gx (K-split) | hist+rank ---------------
template <typename T>
__device__ void cvt_body(int id, const void* Whf_, const void* Whb_, float* whf) {
    if (id >= 2 * HD * G3) return;
    int d = id / (HD * G3), r = id % (HD * G3);
    const T* W = (const T*)(d ? Whb_ : Whf_);
    whf[id] = ld(W, (size_t)r);
}

template <typename T>
__device__ void gx2_body(int bx2, const int* questions, const void* emb_word_,
                         const void* Wxf_, const void* bxf_,
                         const void* Wxb_, const void* bxb_, float* gx,
                         float* xs, float* psum) {
    int tid = threadIdx.x;
    int jt = bx2 % 6;
    int rid = bx2 / 6;                  // 0..255
    int step = rid & 31;
    int b = (rid >> 5) & 3;
    int d = rid >> 7;
    int t = d ? (TT - 1 - step) : step;
    int tok = questions[b * TT + t];
    const T* row = (const T*)emb_word_ + (size_t)tok * DW;
    for (int k = tid; k < DW; k += 256) xs[k] = ld(row, (size_t)k);
    __syncthreads();
    int lane = tid & 63, phase = tid >> 6;
    int j = jt * 64 + lane;
    const T* Wx = (const T*)(d ? Wxb_ : Wxf_);
    float acc = 0.f;
    int k0 = phase * 75;
#pragma unroll 15
    for (int kk = 0; kk < 75; kk++) {
        int k = k0 + kk;
        acc += xs[k] * ld(Wx, (size_t)k * G3 + j);
    }
    psum[tid] = acc;
    __syncthreads();
    if (phase == 0) {
        const T* bx = (const T*)(d ? bxb_ : bxf_);
        float tot = ld(bx, (size_t)j)
                  + psum[lane] + psum[64 + lane] + psum[128 + lane] + psum[192 + lane];
        gx[(size_t)rid * G3 + j] = tot;
    }
}

__global__ void k_prep(const int* flag, const void* Whf, const void* Whb, float* whf,
                       const int* questions, const void* emb_word,
                       const void* Wxf, const void* bxf,
                       const void* Wxb, const void* bxb, float* gx,
                       const int* edge_dst, int* deg, int* rank) {
    __shared__ float xs[DW];
    __shared__ float psum[256];
    int bx = blockIdx.x;
    int tid = threadIdx.x;
    if (bx < NBLK_CVT) {
        int id = bx * 256 + tid;
        if (*flag) cvt_body<bf16>(id, Whf, Whb, whf);
        else       cvt_body<float>(id, Whf, Whb, whf);
    } else if (bx < NBLK_CVT + NBLK_GX2) {
        int bx2 = bx - NBLK_CVT;
        if (*flag) gx2_body<bf16>(bx2, questions, emb_word, Wxf, bxf, Wxb, bxb, gx, xs, psum);
        else       gx2_body<float>(bx2, questions, emb_word, Wxf, bxf, Wxb, bxb, gx, xs, psum);
    } else {
        int e = (bx - NBLK_CVT - NBLK_GX2) * 256 + tid;
        if (e < NEDGES) rank[e] = atomicAdd(&deg[edge_dst[e]], 1);
    }
}

// ---------------- GRU scan (blocks 0..7) + CSR scan (block 8) --------------
template <typename T>
__device__ void gru_body(const int* questions, const float* gx, const float* whf,
                         const void* bhf_, const void* bhb_, float* qemb,
                         float* hsm, float* ghs) {
    int tid = threadIdx.x;
    int d = blockIdx.x >> 2, b = blockIdx.x & 3;
    int half = tid / G3, j = tid - half * G3;
    const float* wh = whf + (size_t)d * HD * G3 + (size_t)half * 64 * G3 + j;
    float w[64];
#pragma unroll
    for (int m = 0; m < 64; m++) w[m] = wh[(size_t)m * G3];
    const T* bh = (const T*)(d ? bhb_ : bhf_);
    float bhj = (half == 0) ? ld(bh, (size_t)j) : 0.f;
    if (tid < HD) hsm[tid] = 0.f;
    const float* gxb = gx + ((size_t)(d * NB + b)) * TT * G3;
    __syncthreads();
    const float4* h4 = (const float4*)(hsm + half * 64);
    for (int step = 0; step < TT; step++) {
        float acc = bhj;
#pragma unroll
        for (int m4 = 0; m4 < 16; m4++) {
            float4 hp = h4[m4];
            acc = fmaf(hp.x, w[4 * m4 + 0], acc);
            acc = fmaf(hp.y, w[4 * m4 + 1], acc);
            acc = fmaf(hp.z, w[4 * m4 + 2], acc);
            acc = fmaf(hp.w, w[4 * m4 + 3], acc);
        }
        ghs[half * G3 + j] = acc;
        __syncthreads();
        if (tid < HD) {
            const float* gxp = gxb + step * G3;
            int t = d ? (TT - 1 - step) : step;
            bool msk = questions[b * TT + t] != 0;
            float gr = ghs[tid] + ghs[G3 + tid];
            float gz = ghs[HD + tid] + ghs[G3 + HD + tid];
            float gn = ghs[2 * HD + tid] + ghs[G3 + 2 * HD + tid];
            float r = 1.f / (1.f + expf(-(gxp[tid] + gr)));
            float z = 1.f / (1.f + expf(-(gxp[HD + tid] + gz)));
            float n = tanhf(gxp[2 * HD + tid] + r * gn);
            float hn = (1.f - z) * n + z * hsm[tid];
            if (msk) hsm[tid] = hn;
        }
        __syncthreads();
    }
    if (tid < HD) qemb[b * DH + d * HD + tid] = hsm[tid];
}

// exclusive int scan of deg with 768 threads x 27 elems (exact)
__device__ void scan_body(const int* deg, int* offs, int* wtot) {
    int t = threadIdx.x;                 // 0..767
    int lane = t & 63, wave = t >> 6;    // 12 waves
    int c[27];
    int base = t * 27;
    int run = 0;
#pragma unroll
    for (int i = 0; i < 27; i++) {
        int v = (base + i < NNODES) ? deg[base + i] : 0;
        c[i] = run;
        run += v;
    }
    int myrun = run, inc = run;
#pragma unroll
    for (int off = 1; off < 64; off <<= 1) {
        int u = __shfl_up(inc, off, 64);
        if (lane >= off) inc += u;
    }
    if (lane == 63) wtot[wave] = inc;
    __syncthreads();
    if (t == 0) {
        int s = 0;
#pragma unroll
        for (int i = 0; i < 12; i++) { int v = wtot[i]; wtot[i] = s; s += v; }
        offs[NNODES] = s;
    }
    __syncthreads();
    int ebase = wtot[wave] + inc - myrun;
#pragma unroll
    for (int i = 0; i < 27; i++) {
        if (base + i < NNODES) offs[base + i] = ebase + c[i];
    }
}

__global__ __launch_bounds__(2 * G3) void k_gru(const int* flag, const int* questions,
                                                const float* gx, const float* whf,
                                                const void* bhf, const void* bhb, float* qemb,
                                                const int* deg, int* offs) {
    __shared__ __align__(16) float hsm[HD];
    __shared__ float ghs[2 * G3];
    __shared__ int wtot[12];
    if (blockIdx.x < 8) {
        if (*flag) gru_body<bf16>(questions, gx, whf, bhf, bhb, qemb, hsm, ghs);
        else       gru_body<float>(questions, gx, whf, bhf, bhb, qemb, hsm, ghs);
    } else {
        scan_body(deg, offs, wtot);
    }
}

// ---------------- q_g = q_emb @ W_hg + b_hg (1 block) ----------------
template <typename T>
__device__ void qg_body(const float* qemb, const void* W_hg_, const void* b_hg_, float* qg) {
    int tid = threadIdx.x;
    int b = tid >> 6, g = tid & 63;
    const T* W = (const T*)W_hg_;
    float acc = ld((const T*)b_hg_, (size_t)g);
#pragma unroll 4
    for (int i = 0; i < DH; i++) acc += qemb[b * DH + i] * ld(W, (size_t)i * G + g);
    qg[b * G + g] = acc;
}
__global__ void k_qg(const int* flag, const float* qemb, const void* W_hg,
                     const void* b_hg, float* qg) {
    if (*flag) qg_body<bf16>(qemb, W_hg, b_hg, qg);
    else       qg_body<float>(qemb, W_hg, b_hg, qg);
}

// ---------------- fused: scatter (no atomics, 8B packed) | attn1 -----------
template <typename T>
__device__ void scatter_body(int e, const int* src, const int* dst, const int* typ,
                             const void* w_comp_, const int* offs, const int* rank,
                             int2* epack) {
    if (e < NEDGES) {
        int pos = offs[dst[e]] + rank[e];
        int2 v;
        v.x = src[e];
        v.y = __float_as_int(ld((const T*)w_comp_, (size_t)typ[e]));
        epack[pos] = v;
    }
}

template <typename T>
__device__ void attn1_body(int nb4, const int* node_descs, const void* emb_desc_,
                           const float* qg, bf16* nf16,
                           float* dsm, float* attn_s, float* qgs) {
    int tid = threadIdx.x;
    if (tid < NB * G) qgs[tid] = qg[tid];
    __syncthreads();
    const T* emb_desc = (const T*)emb_desc_;
    int w = tid >> 6, lane = tid & 63;
    int n = nb4 * 4 + w;
    float dreg[DLEN];
    const int* nd = node_descs + n * DLEN;
    float* dw = dsm + (size_t)w * DLEN * 68;
#pragma unroll
    for (int l = 0; l < DLEN; l++) {
        int idx = nd[l];
        float v = ld(emb_desc, (size_t)idx * G + lane);
        dreg[l] = v;
        dw[l * 68 + lane] = v;
    }
    int lb = lane >> 4, ll = lane & 15;
    float acc = 0.f;
#pragma unroll
    for (int i = 0; i < 16; i++) {
        float4 a = *(const float4*)&dw[ll * 68 + 4 * i];
        float4 q = *(const float4*)&qgs[lb * G + 4 * i];
        acc = fmaf(a.x, q.x, acc);
        acc = fmaf(a.y, q.y, acc);
        acc = fmaf(a.z, q.z, acc);
        acc = fmaf(a.w, q.w, acc);
    }
    float mx = acc;
#pragma unroll
    for (int off = 1; off < 16; off <<= 1) mx = fmaxf(mx, __shfl_xor(mx, off, 64));
    float e = expf(acc - mx);
    float s = e;
#pragma unroll
    for (int off = 1; off < 16; off <<= 1) s += __shfl_xor(s, off, 64);
    attn_s[w * 64 + lane] = e / s;
#pragma unroll
    for (int b = 0; b < NB; b++) {
        float a = 0.f;
#pragma unroll
        for (int l = 0; l < DLEN; l++) a += attn_s[w * 64 + b * 16 + l] * dreg[l];
        nf16[((size_t)b * NNODES + n) * G + lane] = __float2bfloat16(a);
    }
}

__global__ __launch_bounds__(256) void k_sc_attn1(const int* flag,
                                                  const int* src, const int* dst, const int* typ,
                                                  const void* w_comp, const int* offs,
                                                  const int* rank, int2* epack,
                                                  const int* node_descs, const void* emb_desc,
                                                  const float* qg, bf16* nf16) {
    __shared__ __align__(16) float dsm[4 * DLEN * 68];
    __shared__ float attn_s[4 * 64];
    __shared__ __align__(16) float qgs[NB * G];
    int bx = blockIdx.x;
    if (bx < NBLK_SCAT) {
        int e = bx * 256 + threadIdx.x;
        if (*flag) scatter_body<bf16>(e, src, dst, typ, w_comp, offs, rank, epack);
        else       scatter_body<float>(e, src, dst, typ, w_comp, offs, rank, epack);
    } else {
        int nb4 = bx - NBLK_SCAT;
        if (*flag) attn1_body<bf16>(nb4, node_descs, emb_desc, qg, nf16, dsm, attn_s, qgs);
        else       attn1_body<float>(nb4, node_descs, emb_desc, qg, nf16, dsm, attn_s, qgs);
    }
}

// ---------------- hb = nf16 @ bases[0] : tiled register GEMM, bf16 out -----
template <typename T>
__device__ void hbg_body(const bf16* nf16, const void* bases_, bf16* hb16,
                         float* as, float* bs) {
    int tid = threadIdx.x;
    const T* bases = (const T*)bases_;
    for (int i = tid; i < G * G; i += 256) bs[(i >> 6) * 68 + (i & 63)] = ld(bases, (size_t)i);
    size_t r0 = (size_t)blockIdx.x * 64;
    const bf4* gA = (const bf4*)(nf16 + r0 * G);
#pragma unroll
    for (int i = 0; i < 4; i++) {
        int c = tid + i * 256;
        int row = c >> 4, col4 = c & 15;
        bf4 v = gA[c];
        float4 f;
        f.x = __bfloat162float(v.x);
        f.y = __bfloat162float(v.y);
        f.z = __bfloat162float(v.z);
        f.w = __bfloat162float(v.w);
        *(float4*)&as[row * 68 + col4 * 4] = f;
    }
    __syncthreads();
    int tx = tid & 15, ty = tid >> 4;
    float acc[4][4];
#pragma unroll
    for (int i = 0; i < 4; i++)
#pragma unroll
        for (int j = 0; j < 4; j++) acc[i][j] = 0.f;
#pragma unroll 4
    for (int g4 = 0; g4 < 16; g4++) {
        float4 b0 = *(const float4*)&bs[(4 * g4 + 0) * 68 + tx * 4];
        float4 b1 = *(const float4*)&bs[(4 * g4 + 1) * 68 + tx * 4];
        float4 b2 = *(const float4*)&bs[(4 * g4 + 2) * 68 + tx * 4];
        float4 b3 = *(const float4*)&bs[(4 * g4 + 3) * 68 + tx * 4];
#pragma unroll
        for (int i = 0; i < 4; i++) {
            float4 a = *(const float4*)&as[(ty * 4 + i) * 68 + g4 * 4];
            acc[i][0] = fmaf(a.x, b0.x, acc[i][0]);
            acc[i][0] = fmaf(a.y, b1.x, acc[i][0]);
            acc[i][0] = fmaf(a.z, b2.x, acc[i][0]);
            acc[i][0] = fmaf(a.w, b3.x, acc[i][0]);
            acc[i][1] = fmaf(a.x, b0.y, acc[i][1]);
            acc[i][1] = fmaf(a.y, b1.y, acc[i][1]);
            acc[i][1] = fmaf(a.z, b2.y, acc[i][1]);
            acc[i][1] = fmaf(a.w, b3.y, acc[i][1]);
            acc[i][2] = fmaf(a.x, b0.z, acc[i][2]);
            acc[i][2] = fmaf(a.y, b1.z, acc[i][2]);
            acc[i][2] = fmaf(a.z, b2.z, acc[i][2]);
            acc[i][2] = fmaf(a.w, b3.z, acc[i][2]);
            acc[i][3] = fmaf(a.x, b0.w, acc[i][3]);
            acc[i][3] = fmaf(a.y, b1.w, acc[i][3]);
            acc[i][3] = fmaf(a.z, b2.w, acc[i][3]);
            acc[i][3] = fmaf(a.w, b3.w, acc[i][3]);
        }
    }
#pragma unroll
    for (int i = 0; i < 4; i++) {
        size_t r = r0 + ty * 4 + i;
        int b = (int)(r / NNODES);
        int n = (int)(r - (size_t)b * NNODES);
        bf4 o;
        o.x = __float2bfloat16(acc[i][0]);
        o.y = __float2bfloat16(acc[i][1]);
        o.z = __float2bfloat16(acc[i][2]);
        o.w = __float2bfloat16(acc[i][3]);
        *(bf4*)&hb16[((size_t)n * NB + b) * G + tx * 4] = o;
    }
}
__global__ __launch_bounds__(256) void k_hbg(const int* flag, const bf16* nf16,
                                             const void* bases, bf16* hb16) {
    __shared__ __align__(16) float as[64 * 68];
    __shared__ __align__(16) float bs[64 * 68];
    if (*flag) hbg_body<bf16>(nf16, bases, hb16, as, bs);
    else       hbg_body<float>(nf16, bases, hb16, as, bs);
}

// ---------------- RGCN aggregate: packed edges, 16/8/4/1 cascade -----------
template <typename T>
__device__ void agg_body(const bf16* hb16, const int* offs, const int2* epack,
                         const void* bias_, bf16* out_nf16) {
    int tid = threadIdx.x;
    int b = tid >> 6, g = tid & 63;
    int dn = blockIdx.x;
    int s0 = offs[dn], s1 = offs[dn + 1];
    int boff = b * G + g;
    float acc = 0.f;
    int p = s0;
    for (; p + 15 < s1; p += 16) {
        int2 ev[16]; float x[16];
#pragma unroll
        for (int k = 0; k < 16; k++) ev[k] = epack[p + k];
#pragma unroll
        for (int k = 0; k < 16; k++)
            x[k] = __bfloat162float(hb16[(size_t)ev[k].x * (NB * G) + boff]);
#pragma unroll
        for (int k = 0; k < 16; k++) acc += __int_as_float(ev[k].y) * x[k];
    }
    for (; p + 7 < s1; p += 8) {
        int2 ev[8]; float x[8];
#pragma unroll
        for (int k = 0; k < 8; k++) ev[k] = epack[p + k];
#pragma unroll
        for (int k = 0; k < 8; k++)
            x[k] = __bfloat162float(hb16[(size_t)ev[k].x * (NB * G) + boff]);
#pragma unroll
        for (int k = 0; k < 8; k++) acc += __int_as_float(ev[k].y) * x[k];
    }
    for (; p + 3 < s1; p += 4) {
        int2 ev[4]; float x[4];
#pragma unroll
        for (int k = 0; k < 4; k++) ev[k] = epack[p + k];
#pragma unroll
        for (int k = 0; k < 4; k++)
            x[k] = __bfloat162float(hb16[(size_t)ev[k].x * (NB * G) + boff]);
#pragma unroll
        for (int k = 0; k < 4; k++) acc += __int_as_float(ev[k].y) * x[k];
    }
    for (; p < s1; p++) {
        int2 ev = epack[p];
        acc += __int_as_float(ev.y) * __bfloat162float(hb16[(size_t)ev.x * (NB * G) + boff]);
    }
    out_nf16[((size_t)b * NNODES + dn) * G + g] =
        __float2bfloat16(relu(acc + ld((const T*)bias_, (size_t)g)));
}
__global__ __launch_bounds__(256) void k_agg(const int* flag, const bf16* hb16, const int* offs,
                                             const int2* epack, const void* bias,
                                             bf16* out_nf16) {
    if (*flag) agg_body<bf16>(hb16, offs, epack, bias, out_nf16);
    else       agg_body<float>(hb16, offs, epack, bias, out_nf16);
}

// ---------------- attn2: single-pass online softmax over bf16 rg -----------
__device__ __forceinline__ void a2_update(float& M, float& L, float& A, float p, float v) {
    if (p > M) {
        float s = expf(M - p);
        A *= s; L *= s; M = p;
    }
    float e = expf(p - M);
    L += e;
    A = fmaf(e, v, A);
}

__global__ __launch_bounds__(256) void k_attn2(const bf16* rg, const float* qg, float* part) {
    int tid = threadIdx.x;
    int b = tid >> 6, lane = tid & 63;
    float q = qg[b * G + lane];
    int chunk = (NNODES + A2BLK - 1) / A2BLK;
    int n0 = blockIdx.x * chunk;
    int n1 = min(n0 + chunk, NNODES);
    const bf16* base = rg + (size_t)b * NNODES * G + lane;
    float M = -3.4e38f, L = 0.f, A = 0.f;
    int n = n0;
    for (; n + 3 < n1; n += 4) {
        float v0 = __bfloat162float(base[(size_t)(n + 0) * G]);
        float v1 = __bfloat162float(base[(size_t)(n + 1) * G]);
        float v2 = __bfloat162float(base[(size_t)(n + 2) * G]);
        float v3 = __bfloat162float(base[(size_t)(n + 3) * G]);
        float p0 = v0 * q, p1 = v1 * q, p2 = v2 * q, p3 = v3 * q;
#pragma unroll
        for (int off = 32; off >= 1; off >>= 1) {
            p0 += __shfl_xor(p0, off, 64);
            p1 += __shfl_xor(p1, off, 64);
            p2 += __shfl_xor(p2, off, 64);
            p3 += __shfl_xor(p3, off, 64);
        }
        a2_update(M, L, A, p0, v0);
        a2_update(M, L, A, p1, v1);
        a2_update(M, L, A, p2, v2);
        a2_update(M, L, A, p3, v3);
    }
    for (; n < n1; n++) {
        float v = __bfloat162float(base[(size_t)n * G]);
        float p = v * q;
#pragma unroll
        for (int off = 32; off >= 1; off >>= 1) p += __shfl_xor(p, off, 64);
        a2_update(M, L, A, p, v);
    }
    float* pp = part + ((size_t)blockIdx.x * NB + b) * 66;
    if (lane == 0) { pp[0] = M; pp[1] = L; }
    pp[2 + lane] = A;
}

// stage-1 merge: A2BLK -> A2MID partials
__global__ void k_attn2m(const float* part, float* part2) {
    int tid = threadIdx.x;
    int b = tid >> 6, lane = tid & 63;
    int grp = blockIdx.x;
    float M = -3.4e38f, L = 0.f, A = 0.f;
    for (int i = 0; i < A2BLK / A2MID; i++) {
        const float* pp = part + ((size_t)(grp * (A2BLK / A2MID) + i) * NB + b) * 66;
        float m = pp[0], l = pp[1], a = pp[2 + lane];
        float mn = fmaxf(M, m);
        float e1 = expf(M - mn), e2 = expf(m - mn);
        A = A * e1 + a * e2;
        L = L * e1 + l * e2;
        M = mn;
    }
    float* pq = part2 + ((size_t)grp * NB + b) * 66;
    if (lane == 0) { pq[0] = M; pq[1] = L; }
    pq[2 + lane] = A;
}

// ---------------- fc1 with inline final attn2 merge ----------------
template <typename T>
__device__ void fc1_body(const float* part2, const float* qemb,
                         const void* W1_, const void* b1_, float* hid,
                         float* feat, float* psum) {
    int tid = threadIdx.x;
    int b = blockIdx.x >> 4, tile = blockIdx.x & 15;
    if (tid < 64) {
        float M = -3.4e38f, L = 0.f, A = 0.f;
        for (int p = 0; p < A2MID; p++) {
            const float* pp = part2 + ((size_t)p * NB + b) * 66;
            float m = pp[0], l = pp[1], a = pp[2 + tid];
            float mn = fmaxf(M, m);
            float e1 = expf(M - mn), e2 = expf(m - mn);
            A = A * e1 + a * e2;
            L = L * e1 + l * e2;
            M = mn;
        }
        feat[tid] = A / L;
        feat[tid + 256] = qemb[b * DH + tid + 192];
    } else {
        feat[tid] = qemb[b * DH + tid - G];
    }
    __syncthreads();
    int lane = tid & 63, phase = tid >> 6;
    int u = tile * 64 + lane;
    const T* W1 = (const T*)W1_;
    float acc = 0.f;
#pragma unroll 8
    for (int kk = 0; kk < 80; kk++) {
        int k = phase * 80 + kk;
        acc += feat[k] * ld(W1, (size_t)k * 1024 + u);
    }
    psum[tid] = acc;
    __syncthreads();
    if (phase == 0) {
        float tot = psum[lane] + psum[64 + lane] + psum[128 + lane] + psum[192 + lane]
                  + ld((const T*)b1_, (size_t)u);
        hid[b * 1024 + u] = relu(tot);
    }
}
__global__ __launch_bounds__(256) void k_fc1(const int* flag, const float* part2,
                                             const float* qemb, const void* W1, const void* b1,
                                             float* hid) {
    __shared__ float feat[320];
    __shared__ float psum[256];
    if (*flag) fc1_body<bf16>(part2, qemb, W1, b1, hid, feat, psum);
    else       fc1_body<float>(part2, qemb, W1, b1, hid, feat, psum);
}

// ---------------- classifier: fc2, batched c-tile ----------------
template <typename T>
__device__ void fc2_body(const float* hid, const void* W2_, const void* b2_, void* out_,
                         float* hs, float* psum) {
    int tid = threadIdx.x;
    int tile = blockIdx.x;
#pragma unroll
    for (int i = 0; i < 16; i++) hs[tid + 256 * i] = hid[tid + 256 * i];
    __syncthreads();
    int lane = tid & 63, phase = tid >> 6;
    int c = tile * 64 + lane;
    bool ok = (c < NCLS);
    const T* W2 = (const T*)W2_;
    float a0 = 0.f, a1 = 0.f, a2 = 0.f, a3 = 0.f;
    if (ok) {
#pragma unroll 8
        for (int uu = 0; uu < 256; uu++) {
            int u = phase * 256 + uu;
            float w = ld(W2, (size_t)u * NCLS + c);
            a0 += hs[u] * w;
            a1 += hs[1024 + u] * w;
            a2 += hs[2048 + u] * w;
            a3 += hs[3072 + u] * w;
        }
    }
    psum[tid] = a0;
    psum[256 + tid] = a1;
    psum[512 + tid] = a2;
    psum[768 + tid] = a3;
    __syncthreads();
    if (phase == 0 && ok) {
        float bb = ld((const T*)b2_, (size_t)c);
#pragma unroll
        for (int b = 0; b < NB; b++) {
            float* ps = psum + b * 256;
            float tot = ps[lane] + ps[64 + lane] + ps[128 + lane] + ps[192 + lane] + bb;
            st((T*)out_, (size_t)b * NCLS + c, tot);
        }
    }
}
__global__ __launch_bounds__(256) void k_fc2(const int* flag, const float* hid,
                                             const void* W2, const void* b2v, void* out) {
    __shared__ float hs[4096];
    __shared__ float psum[1024];
    if (*flag) fc2_body<bf16>(hid, W2, b2v, out, hs, psum);
    else       fc2_body<float>(hid, W2, b2v, out, hs, psum);
}

extern "C" void kernel_launch(void* const* d_in, const int* in_sizes, int n_in,
                              void* d_out, int out_size, void* d_ws, size_t ws_size,
                              hipStream_t stream) {
    const int* questions  = (const int*)d_in[0];
    const int* node_descs = (const int*)d_in[1];
    const int* edge_src   = (const int*)d_in[2];
    const int* edge_dst   = (const int*)d_in[3];
    const int* edge_type  = (const int*)d_in[4];
    const void* emb_word  = d_in[5];
    const void* emb_desc  = d_in[6];
    const void* Wx_f = d_in[7];
    const void* Wh_f = d_in[8];
    const void* bx_f = d_in[9];
    const void* bh_f = d_in[10];
    const void* Wx_b = d_in[11];
    const void* Wh_b = d_in[12];
    const void* bx_b = d_in[13];
    const void* bh_b = d_in[14];
    const void* W_hg = d_in[15];
    const void* b_hg = d_in[16];
    const void* bases = d_in[17];
    const void* w_comp = d_in[18];
    const void* rgcn_bias = d_in[19];
    const void* W1 = d_in[20];
    const void* b1 = d_in[21];
    const void* W2 = d_in[22];
    const void* b2 = d_in[23];

    float* ws = (float*)d_ws;
    int*      flag  = (int*)(ws + OFF_FLAG);
    float*    gx    = ws + OFF_GX;
    float*    whf   = ws + OFF_WHF;
    float*    qemb  = ws + OFF_QEMB;
    float*    qg    = ws + OFF_QG;
    bf16*     nf16  = (bf16*)(ws + OFF_NF);
    bf16*     hb16  = (bf16*)(ws + OFF_HB);
    float*    part  = ws + OFF_PART;
    float*    part2 = ws + OFF_PART2;
    int*      deg   = (int*)(ws + OFF_DEG);
    int*      offs  = (int*)(ws + OFF_OFFS);
    int*      rank  = (int*)(ws + OFF_RANK);
    int2*     epack = (int2*)(ws + OFF_EPACK);
    float*    hid   = ws + OFF_HID;

    hipLaunchKernelGGL(k_init, dim3(80), dim3(256), 0, stream,
                       (const unsigned*)emb_word, flag, deg);
    hipLaunchKernelGGL(k_prep, dim3(NBLK_CVT + NBLK_GX2 + NBLK_HIST), dim3(256), 0, stream,
                       flag, Wh_f, Wh_b, whf,
                       questions, emb_word, Wx_f, bx_f, Wx_b, bx_b, gx,
                       edge_dst, deg, rank);
    hipLaunchKernelGGL(k_gru, dim3(9), dim3(2 * G3), 0, stream,
                       flag, questions, gx, whf, bh_f, bh_b, qemb, deg, offs);
    hipLaunchKernelGGL(k_qg, dim3(1), dim3(256), 0, stream, flag, qemb, W_hg, b_hg, qg);
    hipLaunchKernelGGL(k_sc_attn1, dim3(NBLK_SCAT + NNODES / 4), dim3(256), 0, stream,
                       flag, edge_src, edge_dst, edge_type, w_comp, offs, rank, epack,
                       node_descs, emb_desc, qg, nf16);
    hipLaunchKernelGGL(k_hbg, dim3(NB * NNODES / 64), dim3(256), 0, stream,
                       flag, nf16, bases, hb16);
    hipLaunchKernelGGL(k_agg, dim3(NNODES), dim3(256), 0, stream,
                       flag, hb16, offs, epack, rgcn_bias, nf16);
    hipLaunchKernelGGL(k_attn2, dim3(A2BLK), dim3(256), 0, stream, nf16, qg, part);
    hipLaunchKernelGGL(k_attn2m, dim3(A2MID), dim3(256), 0, stream, part, part2);
    hipLaunchKernelGGL(k_fc1, dim3(NB * 16), dim3(256), 0, stream,
                       flag, part2, qemb, W1, b1, hid);
    hipLaunchKernelGGL(k_fc2, dim3(32), dim3(256), 0, stream,
                       flag, hid, W2, b2, d_out);
}

// Round 15
// 305.982 us; speedup vs baseline: 1.0560x; 1.0208x over previous
//
#include <hip/hip_runtime.h>
#include <hip/hip_bf16.h>
#include <math.h>

typedef __hip_bfloat16 bf16;

#define NNODES 20000
#define NEDGES 320000
#define DLEN   16
#define G      64
#define DW     300
#define DH     256
#define HD     128
#define G3     384
#define NCLS   2000
#define NB     4
#define TT     32
#define VDESC  30000
#define A2BLK  1024  // attn2 partial blocks
#define A2MID  64    // stage-1 merge outputs

#define NBLK_CVT   384
#define NBLK_GX2   1536   // 256 rows (d,b,step) x 6 j-tiles of 64
#define NBLK_DESCB (VDESC / 16)            // 1875
#define NBLK_HIST  ((NEDGES + 255) / 256)
#define NBLK_SCAT  ((NEDGES + 255) / 256)
#define NBLK_DQ    ((VDESC + 63) / 64)     // 469

__device__ __forceinline__ float ld(const float* p, size_t i) { return p[i]; }
__device__ __forceinline__ float ld(const bf16* p, size_t i) { return __bfloat162float(p[i]); }
__device__ __forceinline__ void st(float* p, size_t i, float v) { p[i] = v; }
__device__ __forceinline__ void st(bf16* p, size_t i, float v) { p[i] = __float2bfloat16(v); }
__device__ __forceinline__ float relu(float x) { return (x < 0.f) ? 0.f : x; }

struct __align__(8) bf4 { bf16 x, y, z, w; };

// ---------------- workspace layout (float words) ----------------
#define OFF_FLAG  ((size_t)0)                         // 4
#define OFF_GX    (OFF_FLAG + 4)                      // 98304
#define OFF_WHF   (OFF_GX   + 2*NB*TT*G3)             // 98304
#define OFF_QEMB  (OFF_WHF  + 2*HD*G3)                // 1024
#define OFF_QG    (OFF_QEMB + NB*DH)                  // 256
#define OFF_NF    (OFF_QG   + NB*G)                   // bf16 post-RGCN [b][n][g]
#define OFF_HB    (OFF_NF   + (size_t)NB*NNODES*G)    // bf16 [n][b][g]
#define OFF_DESCB (OFF_HB   + (size_t)NB*NNODES*G)    // bf16 30000*64 = 960000 words
#define OFF_DQ    (OFF_DESCB + (size_t)VDESC*G/2)     // fp32 30000*4 = 120000
#define OFF_PART  (OFF_DQ   + (size_t)VDESC*NB)       // 1024*4*66
#define OFF_PART2 (OFF_PART + (size_t)A2BLK*NB*66)    // 64*4*66
#define OFF_DEG   (OFF_PART2+ (size_t)A2MID*NB*66)    // int 20000
#define OFF_OFFS  (OFF_DEG  + NNODES)                 // int 20008
#define OFF_RANK  (OFF_OFFS + NNODES + 8)             // int 320000
#define OFF_EPACK (OFF_RANK + NEDGES)                 // int2 x 320000
#define OFF_HID   (OFF_EPACK + 2*(size_t)NEDGES)      // 4096

// ---------------- init: dtype sniff + zero deg ----------------
__global__ void k_init(const unsigned* probe, int* flag, int* deg) {
    int i = blockIdx.x * 256 + threadIdx.x;
    if (i < NNODES) deg[i] = 0;
    if (blockIdx.x == 0 && threadIdx.x < 64) {
        int cnt = 0;
        for (int k = threadIdx.x; k < 4096; k += 64) {
            unsigned lo = probe[k] & 0xFFFFu;
            unsigned e = (lo >> 7) & 0xFFu;
            cnt += (e >= 0x66u && e <= 0x7Eu) ? 1 : 0;
        }
#pragma unroll
        for (int off = 1; off < 64; off <<= 1) cnt += __shfl_xor(cnt, off, 64);
        if (threadIdx.x == 0) *flag = (2 * cnt > 4096) ? 1 : 0;   // 1 = bf16
    }
}

// ---------------- fused prep: cvt | gx (K-split) | descB | hist+rank -------
template <typename T>
__device__ void cvt_body(int id, const void* Whf_, const void* Whb_, float* whf) {
    if (id >= 2 * HD * G3) return;
    int d = id / (HD * G3), r = id % (HD * G3);
    const T* W = (const T*)(d ? Whb_ : Whf_);
    whf[id] = ld(W, (size_t)r);
}

template <typename T>
__device__ void gx2_body(int bx2, const int* questions, const void* emb_word_,
                         const void* Wxf_, const void* bxf_,
                         const void* Wxb_, const void* bxb_, float* gx,
                         float* xs, float* psum) {
    int tid = threadIdx.x;
    int jt = bx2 % 6;
    int rid = bx2 / 6;                  // 0..255
    int step = rid & 31;
    int b = (rid >> 5) & 3;
    int d = rid >> 7;
    int t = d ? (TT - 1 - step) : step;
    int tok = questions[b * TT + t];
    const T* row = (const T*)emb_word_ + (size_t)tok * DW;
    for (int k = tid; k < DW; k += 256) xs[k] = ld(row, (size_t)k);
    __syncthreads();
    int lane = tid & 63, phase = tid >> 6;
    int j = jt * 64 + lane;
    const T* Wx = (const T*)(d ? Wxb_ : Wxf_);
    float acc = 0.f;
    int k0 = phase * 75;
#pragma unroll 15
    for (int kk = 0; kk < 75; kk++) {
        int k = k0 + kk;
        acc += xs[k] * ld(Wx, (size_t)k * G3 + j);
    }
    psum[tid] = acc;
    __syncthreads();
    if (phase == 0) {
        const T* bx = (const T*)(d ? bxb_ : bxf_);
        float tot = ld(bx, (size_t)j)
                  + psum[lane] + psum[64 + lane] + psum[128 + lane] + psum[192 + lane];
        gx[(size_t)rid * G3 + j] = tot;
    }
}

// descB[idx][g] = sum_k emb_desc[idx][k] * bases[k][g]; 16 rows per block.
template <typename T>
__device__ void descb_body(int bx3, const void* emb_desc_, const void* bases_,
                           bf16* descB, float* bsm, float* rsm) {
    int tid = threadIdx.x;
    const T* bases = (const T*)bases_;
    const T* desc = (const T*)emb_desc_;
    for (int i = tid; i < G * G; i += 256) bsm[(i >> 6) * 68 + (i & 63)] = ld(bases, (size_t)i);
    int r0 = bx3 * 16;
    for (int i = tid; i < 16 * G; i += 256) {
        int r = i >> 6, k = i & 63;
        rsm[r * 68 + k] = ld(desc, (size_t)(r0 + r) * G + k);
    }
    __syncthreads();
    int g = tid & 63, slot = tid >> 6;
#pragma unroll
    for (int it = 0; it < 4; it++) {
        int r = slot * 4 + it;
        float acc = 0.f;
#pragma unroll 8
        for (int k = 0; k < G; k++) acc = fmaf(rsm[r * 68 + k], bsm[k * 68 + g], acc);
        descB[(size_t)(r0 + r) * G + g] = __float2bfloat16(acc);
    }
}

__global__ void k_prep(const int* flag, const void* Whf, const void* Whb, float* whf,
                       const int* questions, const void* emb_word,
                       const void* Wxf, const void* bxf,
                       const void* Wxb, const void* bxb, float* gx,
                       const void* emb_desc, const void* bases, bf16* descB,
                       const int* edge_dst, int* deg, int* rank) {
    __shared__ __align__(16) float smem[64 * 68 + 16 * 68];
    int bx = blockIdx.x;
    int tid = threadIdx.x;
    if (bx < NBLK_CVT) {
        int id = bx * 256 + tid;
        if (*flag) cvt_body<bf16>(id, Whf, Whb, whf);
        else       cvt_body<float>(id, Whf, Whb, whf);
    } else if (bx < NBLK_CVT + NBLK_GX2) {
        int bx2 = bx - NBLK_CVT;
        float* xs = smem;
        float* psum = smem + 320;
        if (*flag) gx2_body<bf16>(bx2, questions, emb_word, Wxf, bxf, Wxb, bxb, gx, xs, psum);
        else       gx2_body<float>(bx2, questions, emb_word, Wxf, bxf, Wxb, bxb, gx, xs, psum);
    } else if (bx < NBLK_CVT + NBLK_GX2 + NBLK_DESCB) {
        int bx3 = bx - NBLK_CVT - NBLK_GX2;
        float* bsm = smem;
        float* rsm = smem + 64 * 68;
        if (*flag) descb_body<bf16>(bx3, emb_desc, bases, descB, bsm, rsm);
        else       descb_body<float>(bx3, emb_desc, bases, descB, bsm, rsm);
    } else {
        int e = (bx - NBLK_CVT - NBLK_GX2 - NBLK_DESCB) * 256 + tid;
        if (e < NEDGES) rank[e] = atomicAdd(&deg[edge_dst[e]], 1);
    }
}

// ---------------- GRU scan (blocks 0..7) + CSR scan (block 8) --------------
template <typename T>
__device__ void gru_body(const int* questions, const float* gx, const float* whf,
                         const void* bhf_, const void* bhb_, float* qemb,
                         float* hsm, float* ghs) {
    int tid = threadIdx.x;
    int d = blockIdx.x >> 2, b = blockIdx.x & 3;
    int half = tid / G3, j = tid - half * G3;
    const float* wh = whf + (size_t)d * HD * G3 + (size_t)half * 64 * G3 + j;
    float w[64];
#pragma unroll
    for (int m = 0; m < 64; m++) w[m] = wh[(size_t)m * G3];
    const T* bh = (const T*)(d ? bhb_ : bhf_);
    float bhj = (half == 0) ? ld(bh, (size_t)j) : 0.f;
    if (tid < HD) hsm[tid] = 0.f;
    const float* gxb = gx + ((size_t)(d * NB + b)) * TT * G3;
    __syncthreads();
    const float4* h4 = (const float4*)(hsm + half * 64);
    for (int step = 0; step < TT; step++) {
        float acc = bhj;
#pragma unroll
        for (int m4 = 0; m4 < 16; m4++) {
            float4 hp = h4[m4];
            acc = fmaf(hp.x, w[4 * m4 + 0], acc);
            acc = fmaf(hp.y, w[4 * m4 + 1], acc);
            acc = fmaf(hp.z, w[4 * m4 + 2], acc);
            acc = fmaf(hp.w, w[4 * m4 + 3], acc);
        }
        ghs[half * G3 + j] = acc;
        __syncthreads();
        if (tid < HD) {
            const float* gxp = gxb + step * G3;
            int t = d ? (TT - 1 - step) : step;
            bool msk = questions[b * TT + t] != 0;
            float gr = ghs[tid] + ghs[G3 + tid];
            float gz = ghs[HD + tid] + ghs[G3 + HD + tid];
            float gn = ghs[2 * HD + tid] + ghs[G3 + 2 * HD + tid];
            float r = 1.f / (1.f + expf(-(gxp[tid] + gr)));
            float z = 1.f / (1.f + expf(-(gxp[HD + tid] + gz)));
            float n = tanhf(gxp[2 * HD + tid] + r * gn);
            float hn = (1.f - z) * n + z * hsm[tid];
            if (msk) hsm[tid] = hn;
        }
        __syncthreads();
    }
    if (tid < HD) qemb[b * DH + d * HD + tid] = hsm[tid];
}

// exclusive int scan of deg with 768 threads x 27 elems (exact)
__device__ void scan_body(const int* deg, int* offs, int* wtot) {
    int t = threadIdx.x;                 // 0..767
    int lane = t & 63, wave = t >> 6;    // 12 waves
    int c[27];
    int base = t * 27;
    int run = 0;
#pragma unroll
    for (int i = 0; i < 27; i++) {
        int v = (base + i < NNODES) ? deg[base + i] : 0;
        c[i] = run;
        run += v;
    }
    int myrun = run, inc = run;
#pragma unroll
    for (int off = 1; off < 64; off <<= 1) {
        int u = __shfl_up(inc, off, 64);
        if (lane >= off) inc += u;
    }
    if (lane == 63) wtot[wave] = inc;
    __syncthreads();
    if (t == 0) {
        int s = 0;
#pragma unroll
        for (int i = 0; i < 12; i++) { int v = wtot[i]; wtot[i] = s; s += v; }
        offs[NNODES] = s;
    }
    __syncthreads();
    int ebase = wtot[wave] + inc - myrun;
#pragma unroll
    for (int i = 0; i < 27; i++) {
        if (base + i < NNODES) offs[base + i] = ebase + c[i];
    }
}

__global__ __launch_bounds__(2 * G3) void k_gru(const int* flag, const int* questions,
                                                const float* gx, const float* whf,
                                                const void* bhf, const void* bhb, float* qemb,
                                                const int* deg, int* offs) {
    __shared__ __align__(16) float hsm[HD];
    __shared__ float ghs[2 * G3];
    __shared__ int wtot[12];
    if (blockIdx.x < 8) {
        if (*flag) gru_body<bf16>(questions, gx, whf, bhf, bhb, qemb, hsm, ghs);
        else       gru_body<float>(questions, gx, whf, bhf, bhb, qemb, hsm, ghs);
    } else {
        scan_body(deg, offs, wtot);
    }
}

// ---------------- qg (block 0) + dq = emb_desc @ qg^T (blocks 1..) ---------
template <typename T>
__device__ void qg_compute(const float* qemb, const void* W_hg_, const void* b_hg_,
                           float* out /*256*/) {
    int tid = threadIdx.x;
    int b = tid >> 6, g = tid & 63;
    const T* W = (const T*)W_hg_;
    float acc = ld((const T*)b_hg_, (size_t)g);
#pragma unroll 4
    for (int i = 0; i < DH; i++) acc += qemb[b * DH + i] * ld(W, (size_t)i * G + g);
    out[b * G + g] = acc;
}

template <typename T>
__device__ void dq_body(int chunk, const void* emb_desc_, const float* qgs, float* dq) {
    int tid = threadIdx.x;
    int ii = tid >> 2, b = tid & 3;
    int idx = chunk * 64 + ii;
    if (idx >= VDESC) return;
    const T* row = (const T*)emb_desc_ + (size_t)idx * G;
    const float* q = qgs + b * G;
    float acc = 0.f;
#pragma unroll 8
    for (int k = 0; k < G; k++) acc = fmaf(ld(row, (size_t)k), q[k], acc);
    dq[(size_t)idx * NB + b] = acc;
}

__global__ __launch_bounds__(256) void k_qg_dq(const int* flag, const float* qemb,
                                               const void* W_hg, const void* b_hg, float* qg,
                                               const void* emb_desc, float* dq) {
    __shared__ float qgs[NB * G];
    if (blockIdx.x == 0) {
        if (*flag) qg_compute<bf16>(qemb, W_hg, b_hg, qg);
        else       qg_compute<float>(qemb, W_hg, b_hg, qg);
        return;
    }
    // recompute qg locally (bit-identical) then fill a 64-idx dq chunk
    if (*flag) qg_compute<bf16>(qemb, W_hg, b_hg, qgs);
    else       qg_compute<float>(qemb, W_hg, b_hg, qgs);
    __syncthreads();
    int chunk = blockIdx.x - 1;
    if (*flag) dq_body<bf16>(chunk, emb_desc, qgs, dq);
    else       dq_body<float>(chunk, emb_desc, qgs, dq);
}

// ---------------- fused: scatter (no atomics) | attn1 -> hb16 directly -----
template <typename T>
__device__ void scatter_body(int e, const int* src, const int* dst, const int* typ,
                             const void* w_comp_, const int* offs, const int* rank,
                             int2* epack) {
    if (e < NEDGES) {
        int pos = offs[dst[e]] + rank[e];
        int2 v;
        v.x = src[e];
        v.y = __float_as_int(ld((const T*)w_comp_, (size_t)typ[e]));
        epack[pos] = v;
    }
}

__device__ void attn1_body(int nb4, const int* node_descs, const float* dq,
                           const bf16* descB, bf16* hb16, float* attn_s, int* idxs) {
    int tid = threadIdx.x;
    int w = tid >> 6, lane = tid & 63;
    int n = nb4 * 4 + w;
    int b = lane >> 4, l = lane & 15;
    const int* nd = node_descs + n * DLEN;
    int idx = nd[l];
    float logit = dq[(size_t)idx * NB + b];
    float mx = logit;
#pragma unroll
    for (int off = 1; off < 16; off <<= 1) mx = fmaxf(mx, __shfl_xor(mx, off, 64));
    float e = expf(logit - mx);
    float s = e;
#pragma unroll
    for (int off = 1; off < 16; off <<= 1) s += __shfl_xor(s, off, 64);
    attn_s[w * 64 + lane] = e / s;
    if (lane < 16) idxs[w * 16 + lane] = idx;
    __syncthreads();
    float o0 = 0.f, o1 = 0.f, o2 = 0.f, o3 = 0.f;
#pragma unroll
    for (int ll = 0; ll < DLEN; ll++) {
        int row = idxs[w * 16 + ll];
        float v = __bfloat162float(descB[(size_t)row * G + lane]);
        o0 = fmaf(attn_s[w * 64 + ll], v, o0);
        o1 = fmaf(attn_s[w * 64 + 16 + ll], v, o1);
        o2 = fmaf(attn_s[w * 64 + 32 + ll], v, o2);
        o3 = fmaf(attn_s[w * 64 + 48 + ll], v, o3);
    }
    size_t baseo = (size_t)n * (NB * G) + lane;
    hb16[baseo + 0 * G] = __float2bfloat16(o0);
    hb16[baseo + 1 * G] = __float2bfloat16(o1);
    hb16[baseo + 2 * G] = __float2bfloat16(o2);
    hb16[baseo + 3 * G] = __float2bfloat16(o3);
}

__global__ __launch_bounds__(256) void k_sc_attn1(const int* flag,
                                                  const int* src, const int* dst, const int* typ,
                                                  const void* w_comp, const int* offs,
                                                  const int* rank, int2* epack,
                                                  const int* node_descs, const float* dq,
                                                  const bf16* descB, bf16* hb16) {
    __shared__ float attn_s[4 * 64];
    __shared__ int idxs[4 * DLEN];
    int bx = blockIdx.x;
    if (bx < NBLK_SCAT) {
        int e = bx * 256 + threadIdx.x;
        if (*flag) scatter_body<bf16>(e, src, dst, typ, w_comp, offs, rank, epack);
        else       scatter_body<float>(e, src, dst, typ, w_comp, offs, rank, epack);
    } else {
        attn1_body(bx - NBLK_SCAT, node_descs, dq, descB, hb16, attn_s, idxs);
    }
}

// ---------------- RGCN aggregate: packed edges, 16/8/4/1 cascade -----------
template <typename T>
__device__ void agg_body(const bf16* hb16, const int* offs, const int2* epack,
                         const void* bias_, bf16* out_nf16) {
    int tid = threadIdx.x;
    int b = tid >> 6, g = tid & 63;
    int dn = blockIdx.x;
    int s0 = offs[dn], s1 = offs[dn + 1];
    int boff = b * G + g;
    float acc = 0.f;
    int p = s0;
    for (; p + 15 < s1; p += 16) {
        int2 ev[16]; float x[16];
#pragma unroll
        for (int k = 0; k < 16; k++) ev[k] = epack[p + k];
#pragma unroll
        for (int k = 0; k < 16; k++)
            x[k] = __bfloat162float(hb16[(size_t)ev[k].x * (NB * G) + boff]);
#pragma unroll
        for (int k = 0; k < 16; k++) acc += __int_as_float(ev[k].y) * x[k];
    }
    for (; p + 7 < s1; p += 8) {
        int2 ev[8]; float x[8];
#pragma unroll
        for (int k = 0; k < 8; k++) ev[k] = epack[p + k];
#pragma unroll
        for (int k = 0; k < 8; k++)
            x[k] = __bfloat162float(hb16[(size_t)ev[k].x * (NB * G) + boff]);
#pragma unroll
        for (int k = 0; k < 8; k++) acc += __int_as_float(ev[k].y) * x[k];
    }
    for (; p + 3 < s1; p += 4) {
        int2 ev[4]; float x[4];
#pragma unroll
        for (int k = 0; k < 4; k++) ev[k] = epack[p + k];
#pragma unroll
        for (int k = 0; k < 4; k++)
            x[k] = __bfloat162float(hb16[(size_t)ev[k].x * (NB * G) + boff]);
#pragma unroll
        for (int k = 0; k < 4; k++) acc += __int_as_float(ev[k].y) * x[k];
    }
    for (; p < s1; p++) {
        int2 ev = epack[p];
        acc += __int_as_float(ev.y) * __bfloat162float(hb16[(size_t)ev.x * (NB * G) + boff]);
    }
    out_nf16[((size_t)b * NNODES + dn) * G + g] =
        __float2bfloat16(relu(acc + ld((const T*)bias_, (size_t)g)));
}
__global__ __launch_bounds__(256) void k_agg(const int* flag, const bf16* hb16, const int* offs,
                                             const int2* epack, const void* bias,
                                             bf16* out_nf16) {
    if (*flag) agg_body<bf16>(hb16, offs, epack, bias, out_nf16);
    else       agg_body<float>(hb16, offs, epack, bias, out_nf16);
}

// ---------------- attn2: single-pass online softmax over bf16 rg -----------
__device__ __forceinline__ void a2_update(float& M, float& L, float& A, float p, float v) {
    if (p > M) {
        float s = expf(M - p);
        A *= s; L *= s; M = p;
    }
    float e = expf(p - M);
    L += e;
    A = fmaf(e, v, A);
}

__global__ __launch_bounds__(256) void k_attn2(const bf16* rg, const float* qg, float* part) {
    int tid = threadIdx.x;
    int b = tid >> 6, lane = tid & 63;
    float q = qg[b * G + lane];
    int chunk = (NNODES + A2BLK - 1) / A2BLK;
    int n0 = blockIdx.x * chunk;
    int n1 = min(n0 + chunk, NNODES);
    const bf16* base = rg + (size_t)b * NNODES * G + lane;
    float M = -3.4e38f, L = 0.f, A = 0.f;
    int n = n0;
    for (; n + 3 < n1; n += 4) {
        float v0 = __bfloat162float(base[(size_t)(n + 0) * G]);
        float v1 = __bfloat162float(base[(size_t)(n + 1) * G]);
        float v2 = __bfloat162float(base[(size_t)(n + 2) * G]);
        float v3 = __bfloat162float(base[(size_t)(n + 3) * G]);
        float p0 = v0 * q, p1 = v1 * q, p2 = v2 * q, p3 = v3 * q;
#pragma unroll
        for (int off = 32; off >= 1; off >>= 1) {
            p0 += __shfl_xor(p0, off, 64);
            p1 += __shfl_xor(p1, off, 64);
            p2 += __shfl_xor(p2, off, 64);
            p3 += __shfl_xor(p3, off, 64);
        }
        a2_update(M, L, A, p0, v0);
        a2_update(M, L, A, p1, v1);
        a2_update(M, L, A, p2, v2);
        a2_update(M, L, A, p3, v3);
    }
    for (; n < n1; n++) {
        float v = __bfloat162float(base[(size_t)n * G]);
        float p = v * q;
#pragma unroll
        for (int off = 32; off >= 1; off >>= 1) p += __shfl_xor(p, off, 64);
        a2_update(M, L, A, p, v);
    }
    float* pp = part + ((size_t)blockIdx.x * NB + b) * 66;
    if (lane == 0) { pp[0] = M; pp[1] = L; }
    pp[2 + lane] = A;
}

// stage-1 merge: A2BLK -> A2MID partials
__global__ void k_attn2m(const float* part, float* part2) {
    int tid = threadIdx.x;
    int b = tid >> 6, lane = tid & 63;
    int grp = blockIdx.x;
    float M = -3.4e38f, L = 0.f, A = 0.f;
    for (int i = 0; i < A2BLK / A2MID; i++) {
        const float* pp = part + ((size_t)(grp * (A2BLK / A2MID) + i) * NB + b) * 66;
        float m = pp[0], l = pp[1], a = pp[2 + lane];
        float mn = fmaxf(M, m);
        float e1 = expf(M - mn), e2 = expf(m - mn);
        A = A * e1 + a * e2;
        L = L * e1 + l * e2;
        M = mn;
    }
    float* pq = part2 + ((size_t)grp * NB + b) * 66;
    if (lane == 0) { pq[0] = M; pq[1] = L; }
    pq[2 + lane] = A;
}

// ---------------- fc1 with inline final attn2 merge ----------------
template <typename T>
__device__ void fc1_body(const float* part2, const float* qemb,
                         const void* W1_, const void* b1_, float* hid,
                         float* feat, float* psum) {
    int tid = threadIdx.x;
    int b = blockIdx.x >> 4, tile = blockIdx.x & 15;
    if (tid < 64) {
        float M = -3.4e38f, L = 0.f, A = 0.f;
        for (int p = 0; p < A2MID; p++) {
            const float* pp = part2 + ((size_t)p * NB + b) * 66;
            float m = pp[0], l = pp[1], a = pp[2 + tid];
            float mn = fmaxf(M, m);
            float e1 = expf(M - mn), e2 = expf(m - mn);
            A = A * e1 + a * e2;
            L = L * e1 + l * e2;
            M = mn;
        }
        feat[tid] = A / L;
        feat[tid + 256] = qemb[b * DH + tid + 192];
    } else {
        feat[tid] = qemb[b * DH + tid - G];
    }
    __syncthreads();
    int lane = tid & 63, phase = tid >> 6;
    int u = tile * 64 + lane;
    const T* W1 = (const T*)W1_;
    float acc = 0.f;
#pragma unroll 8
    for (int kk = 0; kk < 80; kk++) {
        int k = phase * 80 + kk;
        acc += feat[k] * ld(W1, (size_t)k * 1024 + u);
    }
    psum[tid] = acc;
    __syncthreads();
    if (phase == 0) {
        float tot = psum[lane] + psum[64 + lane] + psum[128 + lane] + psum[192 + lane]
                  + ld((const T*)b1_, (size_t)u);
        hid[b * 1024 + u] = relu(tot);
    }
}
__global__ __launch_bounds__(256) void k_fc1(const int* flag, const float* part2,
                                             const float* qemb, const void* W1, const void* b1,
                                             float* hid) {
    __shared__ float feat[320];
    __shared__ float psum[256];
    if (*flag) fc1_body<bf16>(part2, qemb, W1, b1, hid, feat, psum);
    else       fc1_body<float>(part2, qemb, W1, b1, hid, feat, psum);
}

// ---------------- classifier: fc2, batched c-tile ----------------
template <typename T>
__device__ void fc2_body(const float* hid, const void* W2_, const void* b2_, void* out_,
                         float* hs, float* psum) {
    int tid = threadIdx.x;
    int tile = blockIdx.x;
#pragma unroll
    for (int i = 0; i < 16; i++) hs[tid + 256 * i] = hid[tid + 256 * i];
    __syncthreads();
    int lane = tid & 63, phase = tid >> 6;
    int c = tile * 64 + lane;
    bool ok = (c < NCLS);
    const T* W2 = (const T*)W2_;
    float a0 = 0.f, a1 = 0.f, a2 = 0.f, a3 = 0.f;
    if (ok) {
#pragma unroll 8
        for (int uu = 0; uu < 256; uu++) {
            int u = phase * 256 + uu;
            float w = ld(W2, (size_t)u * NCLS + c);
            a0 += hs[u] * w;
            a1 += hs[1024 + u] * w;
            a2 += hs[2048 + u] * w;
            a3 += hs[3072 + u] * w;
        }
    }
    psum[tid] = a0;
    psum[256 + tid] = a1;
    psum[512 + tid] = a2;
    psum[768 + tid] = a3;
    __syncthreads();
    if (phase == 0 && ok) {
        float bb = ld((const T*)b2_, (size_t)c);
#pragma unroll
        for (int b = 0; b < NB; b++) {
            float* ps = psum + b * 256;
            float tot = ps[lane] + ps[64 + lane] + ps[128 + lane] + ps[192 + lane] + bb;
            st((T*)out_, (size_t)b * NCLS + c, tot);
        }
    }
}
__global__ __launch_bounds__(256) void k_fc2(const int* flag, const float* hid,
                                             const void* W2, const void* b2v, void* out) {
    __shared__ float hs[4096];
    __shared__ float psum[1024];
    if (*flag) fc2_body<bf16>(hid, W2, b2v, out, hs, psum);
    else       fc2_body<float>(hid, W2, b2v, out, hs, psum);
}

extern "C" void kernel_launch(void* const* d_in, const int* in_sizes, int n_in,
                              void* d_out, int out_size, void* d_ws, size_t ws_size,
                              hipStream_t stream) {
    const int* questions  = (const int*)d_in[0];
    const int* node_descs = (const int*)d_in[1];
    const int* edge_src   = (const int*)d_in[2];
    const int* edge_dst   = (const int*)d_in[3];
    const int* edge_type  = (const int*)d_in[4];
    const void* emb_word  = d_in[5];
    const void* emb_desc  = d_in[6];
    const void* Wx_f = d_in[7];
    const void* Wh_f = d_in[8];
    const void* bx_f = d_in[9];
    const void* bh_f = d_in[10];
    const void* Wx_b = d_in[11];
    const void* Wh_b = d_in[12];
    const void* bx_b = d_in[13];
    const void* bh_b = d_in[14];
    const void* W_hg = d_in[15];
    const void* b_hg = d_in[16];
    const void* bases = d_in[17];
    const void* w_comp = d_in[18];
    const void* rgcn_bias = d_in[19];
    const void* W1 = d_in[20];
    const void* b1 = d_in[21];
    const void* W2 = d_in[22];
    const void* b2 = d_in[23];

    float* ws = (float*)d_ws;
    int*      flag  = (int*)(ws + OFF_FLAG);
    float*    gx    = ws + OFF_GX;
    float*    whf   = ws + OFF_WHF;
    float*    qemb  = ws + OFF_QEMB;
    float*    qg    = ws + OFF_QG;
    bf16*     nf16  = (bf16*)(ws + OFF_NF);
    bf16*     hb16  = (bf16*)(ws + OFF_HB);
    bf16*     descB = (bf16*)(ws + OFF_DESCB);
    float*    dq    = ws + OFF_DQ;
    float*    part  = ws + OFF_PART;
    float*    part2 = ws + OFF_PART2;
    int*      deg   = (int*)(ws + OFF_DEG);
    int*      offs  = (int*)(ws + OFF_OFFS);
    int*      rank  = (int*)(ws + OFF_RANK);
    int2*     epack = (int2*)(ws + OFF_EPACK);
    float*    hid   = ws + OFF_HID;

    hipLaunchKernelGGL(k_init, dim3(80), dim3(256), 0, stream,
                       (const unsigned*)emb_word, flag, deg);
    hipLaunchKernelGGL(k_prep,
                       dim3(NBLK_CVT + NBLK_GX2 + NBLK_DESCB + NBLK_HIST), dim3(256), 0, stream,
                       flag, Wh_f, Wh_b, whf,
                       questions, emb_word, Wx_f, bx_f, Wx_b, bx_b, gx,
                       emb_desc, bases, descB,
                       edge_dst, deg, rank);
    hipLaunchKernelGGL(k_gru, dim3(9), dim3(2 * G3), 0, stream,
                       flag, questions, gx, whf, bh_f, bh_b, qemb, deg, offs);
    hipLaunchKernelGGL(k_qg_dq, dim3(1 + NBLK_DQ), dim3(256), 0, stream,
                       flag, qemb, W_hg, b_hg, qg, emb_desc, dq);
    hipLaunchKernelGGL(k_sc_attn1, dim3(NBLK_SCAT + NNODES / 4), dim3(256), 0, stream,
                       flag, edge_src, edge_dst, edge_type, w_comp, offs, rank, epack,
                       node_descs, dq, descB, hb16);
    hipLaunchKernelGGL(k_agg, dim3(NNODES), dim3(256), 0, stream,
                       flag, hb16, offs, epack, rgcn_bias, nf16);
    hipLaunchKernelGGL(k_attn2, dim3(A2BLK), dim3(256), 0, stream, nf16, qg, part);
    hipLaunchKernelGGL(k_attn2m, dim3(A2MID), dim3(256), 0, stream, part, part2);
    hipLaunchKernelGGL(k_fc1, dim3(NB * 16), dim3(256), 0, stream,
                       flag, part2, qemb, W1, b1, hid);
    hipLaunchKernelGGL(k_fc2, dim3(32), dim3(256), 0, stream,
                       flag, hid, W2, b2, d_out);
}